// Round 14
// baseline (61.122 us; speedup 1.0000x reference)
//
#include <hip/hip_runtime.h>
#include <cstddef>
#include <cstdint>

#define D_MODEL 512
#define DK 64
#define LQ 1024
#define LK 1024
#define NB 2
#define LN_EPS 1e-6f
#define L2E2 2.8853900817779268f  // 2*log2(e)

// ---------------- projections ----------------
// type 0: qp=q@Wq -> ab4[row][dp] = float4{A_dp, B_dp, A_dp+32, B_dp+32}
//         with A = v_d*e^{-2qp}, B = e^{-2qp}
// type 1: ek=e^{2*(k@Wk)} -> ekT2[batch][dp][j] = float2{ek[dp], ek[dp+32]}
// type 2: vp = v@Wv (f32 row-major)
// ZERO LDS: row values via wave-uniform float4 global loads (s_load_dwordx4,
// the r13-score-proven mechanism); W per-lane coalesced vector loads.
// 256 thr (4 waves), 16 rows/block (4/wave), grid 384.
#define PR_ROWS 16
__global__ __launch_bounds__(256, 4) void proj_kernel(
    const float* __restrict__ q, const float* __restrict__ k,
    const float* __restrict__ v, const float* __restrict__ Wq,
    const float* __restrict__ Wk, const float* __restrict__ Wv,
    const float* __restrict__ v_param, float4* __restrict__ ab4,
    float2* __restrict__ ekT2, float* __restrict__ vp) {
  const int tid = threadIdx.x;
  const int type = blockIdx.x >> 7;  // 128 row-groups per type
  const int r0 = (blockIdx.x & 127) * PR_ROWS;
  const float* __restrict__ in = (type == 0) ? q : (type == 1) ? k : v;
  const float* __restrict__ W = (type == 0) ? Wq : (type == 1) ? Wk : Wv;
  const int lane = tid & 63;
  const int wv = __builtin_amdgcn_readfirstlane(tid >> 6);  // uniform 0..3
  const int rglob = r0 + wv * 4;  // wave's first global row (mult of 4)
  const float* __restrict__ Wl = W + lane;
  // wave-uniform row pointers -> scalar loads
  const float* __restrict__ rp0 = in + (size_t)(rglob + 0) * D_MODEL;
  const float* __restrict__ rp1 = in + (size_t)(rglob + 1) * D_MODEL;
  const float* __restrict__ rp2 = in + (size_t)(rglob + 2) * D_MODEL;
  const float* __restrict__ rp3 = in + (size_t)(rglob + 3) * D_MODEL;
  float c0[4] = {0.f, 0.f, 0.f, 0.f}, c1[4] = {0.f, 0.f, 0.f, 0.f};
#pragma unroll 4
  for (int e = 0; e < D_MODEL; e += 4) {
    float w0 = Wl[(size_t)(e + 0) * DK];
    float w1 = Wl[(size_t)(e + 1) * DK];
    float w2 = Wl[(size_t)(e + 2) * DK];
    float w3 = Wl[(size_t)(e + 3) * DK];
    float4 x0 = *(const float4*)&rp0[e];  // uniform -> s_load_dwordx4
    float4 x1 = *(const float4*)&rp1[e];
    float4 x2 = *(const float4*)&rp2[e];
    float4 x3 = *(const float4*)&rp3[e];
    c0[0] = fmaf(x0.x, w0, c0[0]); c1[0] = fmaf(x0.y, w1, c1[0]);
    c0[0] = fmaf(x0.z, w2, c0[0]); c1[0] = fmaf(x0.w, w3, c1[0]);
    c0[1] = fmaf(x1.x, w0, c0[1]); c1[1] = fmaf(x1.y, w1, c1[1]);
    c0[1] = fmaf(x1.z, w2, c0[1]); c1[1] = fmaf(x1.w, w3, c1[1]);
    c0[2] = fmaf(x2.x, w0, c0[2]); c1[2] = fmaf(x2.y, w1, c1[2]);
    c0[2] = fmaf(x2.z, w2, c0[2]); c1[2] = fmaf(x2.w, w3, c1[2]);
    c0[3] = fmaf(x3.x, w0, c0[3]); c1[3] = fmaf(x3.y, w1, c1[3]);
    c0[3] = fmaf(x3.z, w2, c0[3]); c1[3] = fmaf(x3.w, w3, c1[3]);
  }
  float acc[4];
#pragma unroll
  for (int r = 0; r < 4; ++r) acc[r] = c0[r] + c1[r];
  if (type == 0) {
    float vpar = v_param[lane];
#pragma unroll
    for (int r = 0; r < 4; ++r) {
      float iv = __builtin_amdgcn_exp2f(-L2E2 * acc[r]);
      float A = vpar * iv, B = iv;
      float Ah = __shfl_down(A, 32);  // lane d gets A_{d+32}
      float Bh = __shfl_down(B, 32);
      if (lane < 32)
        ab4[(size_t)(rglob + r) * 32 + lane] = make_float4(A, B, Ah, Bh);
    }
  } else if (type == 1) {
    float e4[4], h4[4];
#pragma unroll
    for (int r = 0; r < 4; ++r) {
      e4[r] = __builtin_amdgcn_exp2f(L2E2 * acc[r]);
      h4[r] = __shfl_down(e4[r], 32);  // lane d gets Ek[d+32]
    }
    if (lane < 32) {
      int b = rglob >> 10, j0 = rglob & 1023;  // rglob%4==0 -> 16B aligned
      float2* bp = ekT2 + (size_t)b * 32 * LK + (size_t)lane * LK + j0;
      *(float4*)bp = make_float4(e4[0], h4[0], e4[1], h4[1]);
      *(float4*)(bp + 2) = make_float4(e4[2], h4[2], e4[3], h4[3]);
    }
  } else {
#pragma unroll
    for (int r = 0; r < 4; ++r) vp[(size_t)(rglob + r) * DK + lane] = acc[r];
  }
}

// ---------------- fused scores + softmax + PV + FC + LN ----------------
// 512 thr (8 waves), RB=4 rows/block, grid 512 -> 16 waves/CU = 4/SIMD
// (r13 lesson: fusion was the lever; this round doubles TLP for latency
// hiding). Score: zero LDS, wave-uniform A/B s_loads, quad-rcp, f32 K;
// thread owns j0 = tid, j1 = tid + 512.
#define RB 4
__global__ __launch_bounds__(512, 4) void attn_kernel(
    const float4* __restrict__ ab4, const float2* __restrict__ ekT2,
    const float* __restrict__ vp, const float* __restrict__ resid,
    const float* __restrict__ Wfc, const float* __restrict__ gamma,
    const float* __restrict__ beta, float* __restrict__ out,
    float* __restrict__ attn_out) {
  __shared__ float sc[RB][LK];                  // 16 KB P rows
  __shared__ float4 pvred[8][RB][16];           // 8 KB PV partials
  __shared__ __align__(16) float ovlT[DK][RB];  // 1 KB, e-major
  __shared__ float red[2][RB][8];               // LN reductions
  __shared__ float mred[RB][8], sred[RB][8];
  const int tid = threadIdx.x;
  const int row0 = blockIdx.x * RB;  // RB | LQ -> single batch per block
  const int batch = row0 >> 10;
  const float2* __restrict__ ekT_b = ekT2 + (size_t)batch * 32 * LK + tid;
  const float* __restrict__ vp_b = vp + (size_t)batch * LK * DK;
  const float4* __restrict__ abr0 = ab4 + (size_t)(row0 + 0) * 32;
  const float4* __restrict__ abr1 = ab4 + (size_t)(row0 + 1) * 32;
  const float4* __restrict__ abr2 = ab4 + (size_t)(row0 + 2) * 32;
  const float4* __restrict__ abr3 = ab4 + (size_t)(row0 + 3) * 32;

  float a0[2] = {0.f, 0.f};  // [jj] per row, static-indexed
  float a1[2] = {0.f, 0.f};
  float a2[2] = {0.f, 0.f};
  float a3[2] = {0.f, 0.f};

#pragma unroll
  for (int qd = 0; qd < 16; ++qd) {  // quad covers dp = 2qd, 2qd+1
    float2 k0[2], k1[2];
    k0[0] = ekT_b[(size_t)(2 * qd + 0) * LK];
    k1[0] = ekT_b[(size_t)(2 * qd + 1) * LK];
    k0[1] = ekT_b[(size_t)(2 * qd + 0) * LK + 512];
    k1[1] = ekT_b[(size_t)(2 * qd + 1) * LK + 512];
    // wave-uniform A/B loads (scalarized)
    float4 P0 = abr0[2 * qd], Q0 = abr0[2 * qd + 1];
    float4 P1 = abr1[2 * qd], Q1 = abr1[2 * qd + 1];
    float4 P2 = abr2[2 * qd], Q2 = abr2[2 * qd + 1];
    float4 P3 = abr3[2 * qd], Q3 = abr3[2 * qd + 1];
#pragma unroll
    for (int jj = 0; jj < 2; ++jj) {
#define QUAD(PP, QQ, ACC)                                                  \
  {                                                                        \
    float x1 = k0[jj].x + PP.y, x2 = k0[jj].y + PP.w;                      \
    float x3 = k1[jj].x + QQ.y, x4 = k1[jj].y + QQ.w;                      \
    float p12 = x1 * x2, p34 = x3 * x4;                                    \
    float n12 = fmaf(PP.z, x1, PP.x * x2);                                 \
    float n34 = fmaf(QQ.z, x3, QQ.x * x4);                                 \
    float num = fmaf(n34, p12, n12 * p34);                                 \
    ACC[jj] = fmaf(num, __builtin_amdgcn_rcpf(p12 * p34), ACC[jj]);        \
  }
      QUAD(P0, Q0, a0)
      QUAD(P1, Q1, a1)
      QUAD(P2, Q2, a2)
      QUAD(P3, Q3, a3)
#undef QUAD
    }
  }

  const int wave = __builtin_amdgcn_readfirstlane(tid >> 6);  // 0..7
  const int lane = tid & 63;

  // softmax over score = C - 2*acc -> shift by min(acc)
  {
    float pm0 = fminf(a0[0], a0[1]);
    float pm1 = fminf(a1[0], a1[1]);
    float pm2 = fminf(a2[0], a2[1]);
    float pm3 = fminf(a3[0], a3[1]);
#pragma unroll
    for (int off = 32; off > 0; off >>= 1) {
      pm0 = fminf(pm0, __shfl_xor(pm0, off));
      pm1 = fminf(pm1, __shfl_xor(pm1, off));
      pm2 = fminf(pm2, __shfl_xor(pm2, off));
      pm3 = fminf(pm3, __shfl_xor(pm3, off));
    }
    if (lane == 0) {
      mred[0][wave] = pm0; mred[1][wave] = pm1;
      mred[2][wave] = pm2; mred[3][wave] = pm3;
    }
    __syncthreads();
    float m0 = 1e30f, m1 = 1e30f, m2 = 1e30f, m3 = 1e30f;
#pragma unroll
    for (int w = 0; w < 8; ++w) {
      m0 = fminf(m0, mred[0][w]); m1 = fminf(m1, mred[1][w]);
      m2 = fminf(m2, mred[2][w]); m3 = fminf(m3, mred[3][w]);
    }
    float s0 = 0.f, s1 = 0.f, s2 = 0.f, s3 = 0.f;
#pragma unroll
    for (int jj = 0; jj < 2; ++jj) {
      a0[jj] = __builtin_amdgcn_exp2f((m0 - a0[jj]) * L2E2); s0 += a0[jj];
      a1[jj] = __builtin_amdgcn_exp2f((m1 - a1[jj]) * L2E2); s1 += a1[jj];
      a2[jj] = __builtin_amdgcn_exp2f((m2 - a2[jj]) * L2E2); s2 += a2[jj];
      a3[jj] = __builtin_amdgcn_exp2f((m3 - a3[jj]) * L2E2); s3 += a3[jj];
    }
#pragma unroll
    for (int off = 32; off > 0; off >>= 1) {
      s0 += __shfl_xor(s0, off); s1 += __shfl_xor(s1, off);
      s2 += __shfl_xor(s2, off); s3 += __shfl_xor(s3, off);
    }
    if (lane == 0) {
      sred[0][wave] = s0; sred[1][wave] = s1;
      sred[2][wave] = s2; sred[3][wave] = s3;
    }
    __syncthreads();
    float t0 = 0.f, t1 = 0.f, t2 = 0.f, t3 = 0.f;
#pragma unroll
    for (int w = 0; w < 8; ++w) {
      t0 += sred[0][w]; t1 += sred[1][w];
      t2 += sred[2][w]; t3 += sred[3][w];
    }
    float i0 = __builtin_amdgcn_rcpf(t0);
    float i1 = __builtin_amdgcn_rcpf(t1);
    float i2 = __builtin_amdgcn_rcpf(t2);
    float i3 = __builtin_amdgcn_rcpf(t3);
    float* __restrict__ ar0 = attn_out + (size_t)(row0 + 0) * LK;
    float* __restrict__ ar1 = attn_out + (size_t)(row0 + 1) * LK;
    float* __restrict__ ar2 = attn_out + (size_t)(row0 + 2) * LK;
    float* __restrict__ ar3 = attn_out + (size_t)(row0 + 3) * LK;
#pragma unroll
    for (int jj = 0; jj < 2; ++jj) {
      float p0 = a0[jj] * i0, p1 = a1[jj] * i1;
      float p2 = a2[jj] * i2, p3 = a3[jj] * i3;
      sc[0][tid + jj * 512] = p0; ar0[tid + jj * 512] = p0;
      sc[1][tid + jj * 512] = p1; ar1[tid + jj * 512] = p1;
      sc[2][tid + jj * 512] = p2; ar2[tid + jj * 512] = p2;
      sc[3][tid + jj * 512] = p3; ar3[tid + jj * 512] = p3;
    }
  }
  __syncthreads();

  // PV: wave owns 128-j slice; vp read once per block per j (serves 4 rows)
  {
    const int jj = lane >> 4, l16 = lane & 15;
    const float4* __restrict__ vp4 = (const float4*)vp_b;
    float4 a[RB];
#pragma unroll
    for (int r = 0; r < RB; ++r) a[r] = make_float4(0.f, 0.f, 0.f, 0.f);
#pragma unroll 4
    for (int it = 0; it < 32; ++it) {
      int j = (wave << 7) + (it << 2) + jj;
      float4 vv = vp4[(size_t)j * (DK / 4) + l16];
#pragma unroll
      for (int r = 0; r < RB; ++r) {
        float pw = sc[r][j];
        a[r].x = fmaf(pw, vv.x, a[r].x);
        a[r].y = fmaf(pw, vv.y, a[r].y);
        a[r].z = fmaf(pw, vv.z, a[r].z);
        a[r].w = fmaf(pw, vv.w, a[r].w);
      }
    }
#pragma unroll
    for (int r = 0; r < RB; ++r) {
      a[r].x += __shfl_xor(a[r].x, 16); a[r].y += __shfl_xor(a[r].y, 16);
      a[r].z += __shfl_xor(a[r].z, 16); a[r].w += __shfl_xor(a[r].w, 16);
      a[r].x += __shfl_xor(a[r].x, 32); a[r].y += __shfl_xor(a[r].y, 32);
      a[r].z += __shfl_xor(a[r].z, 32); a[r].w += __shfl_xor(a[r].w, 32);
    }
    if (jj == 0) {
#pragma unroll
      for (int r = 0; r < RB; ++r) pvred[wave][r][l16] = a[r];
    }
  }
  __syncthreads();
  if (tid < 64) {  // final PV reduce -> transposed ovlT[e][r]
    int r = tid >> 4, l16 = tid & 15;
    float4 s = make_float4(0.f, 0.f, 0.f, 0.f);
#pragma unroll
    for (int w = 0; w < 8; ++w) {
      float4 t = pvred[w][r][l16];
      s.x += t.x; s.y += t.y; s.z += t.z; s.w += t.w;
    }
    ovlT[l16 * 4 + 0][r] = s.x;
    ovlT[l16 * 4 + 1][r] = s.y;
    ovlT[l16 * 4 + 2][r] = s.z;
    ovlT[l16 * 4 + 3][r] = s.w;
  }
  __syncthreads();

  // FC + residual + LN: thread owns column c = tid for 4 rows
  {
    const int c = tid;
    float y[RB];
#pragma unroll
    for (int r = 0; r < RB; ++r)
      y[r] = resid[(size_t)(row0 + r) * D_MODEL + c];
#pragma unroll 4
    for (int e = 0; e < DK; ++e) {
      float w = Wfc[(size_t)e * D_MODEL + c];
      float4 ov = *(const float4*)&ovlT[e][0];
      y[0] = fmaf(ov.x, w, y[0]);
      y[1] = fmaf(ov.y, w, y[1]);
      y[2] = fmaf(ov.z, w, y[2]);
      y[3] = fmaf(ov.w, w, y[3]);
    }
#pragma unroll
    for (int r = 0; r < RB; ++r) {
      float s = y[r];
#pragma unroll
      for (int off = 32; off > 0; off >>= 1) s += __shfl_xor(s, off);
      if (lane == 0) red[0][r][wave] = s;
    }
    __syncthreads();
    float mu[RB];
#pragma unroll
    for (int r = 0; r < RB; ++r) {
      float s = 0.f;
#pragma unroll
      for (int w = 0; w < 8; ++w) s += red[0][r][w];
      mu[r] = s * (1.0f / D_MODEL);
    }
#pragma unroll
    for (int r = 0; r < RB; ++r) {
      float d = y[r] - mu[r];
      float s = d * d;
#pragma unroll
      for (int off = 32; off > 0; off >>= 1) s += __shfl_xor(s, off);
      if (lane == 0) red[1][r][wave] = s;
    }
    __syncthreads();
    float gg = gamma[c], bb = beta[c];
#pragma unroll
    for (int r = 0; r < RB; ++r) {
      float s = 0.f;
#pragma unroll
      for (int w = 0; w < 8; ++w) s += red[1][r][w];
      float var = s * (1.0f / D_MODEL);
      float rstd = rsqrtf(var + LN_EPS);
      out[(size_t)(row0 + r) * D_MODEL + c] = (y[r] - mu[r]) * rstd * gg + bb;
    }
  }
}

extern "C" void kernel_launch(void* const* d_in, const int* in_sizes, int n_in,
                              void* d_out, int out_size, void* d_ws,
                              size_t ws_size, hipStream_t stream) {
  const float* q = (const float*)d_in[0];
  const float* k = (const float*)d_in[1];
  const float* v = (const float*)d_in[2];
  const float* Wq = (const float*)d_in[3];
  const float* Wk = (const float*)d_in[4];
  const float* Wv = (const float*)d_in[5];
  const float* v_param = (const float*)d_in[6];
  const float* Wfc = (const float*)d_in[7];
  const float* gamma = (const float*)d_in[8];
  const float* beta = (const float*)d_in[9];

  float* out = (float*)d_out;                     // [B*LQ*D_MODEL]
  float* attn = out + (size_t)NB * LQ * D_MODEL;  // [B*LQ*LK]

  float* base = (float*)d_ws;
  float4* ab4 = (float4*)base;                    // 2048*32 float4 (1 MB)
  float* p1 = base + (size_t)NB * LQ * 32 * 4;    // floats consumed by ab4
  float2* ekT2 = (float2*)p1;                     // 2*32*1024 float2 (512 KB)
  float* vp = p1 + (size_t)NB * 32 * LK * 2;      // [2048*64]

  hipLaunchKernelGGL(proj_kernel, dim3(3 * 128), dim3(256), 0, stream, q, k, v,
                     Wq, Wk, Wv, v_param, ab4, ekT2, vp);
  hipLaunchKernelGGL(attn_kernel, dim3(NB * LQ / RB), dim3(512), 0, stream,
                     ab4, ekT2, vp, q, Wfc, gamma, beta, out, attn);
}

// Round 15
// 55.710 us; speedup vs baseline: 1.0972x; 1.0972x over previous
//
#include <hip/hip_runtime.h>
#include <cstddef>
#include <cstdint>

#define D_MODEL 512
#define DK 64
#define LQ 1024
#define LK 1024
#define NB 2
#define LN_EPS 1e-6f
#define L2E2 2.8853900817779268f  // 2*log2(e)

// ---------------- projections ----------------
// type 0: qp=q@Wq -> ab4[row][dp] = float4{A_dp, B_dp, A_dp+32, B_dp+32}
//         with A = v_d*e^{-2qp}, B = e^{-2qp}
// type 1: ek=e^{2*(k@Wk)} -> ekT2[batch][dp][j] = float2{ek[dp], ek[dp+32]}
// type 2: vp = v@Wv (f32 row-major)
// r13-proven shape: 256 thr (4 waves), 16 rows/block (4/wave), grid 384,
// rows staged in LDS (b128 broadcasts), W per-lane coalesced.
#define PR_ROWS 16
__global__ __launch_bounds__(256, 4) void proj_kernel(
    const float* __restrict__ q, const float* __restrict__ k,
    const float* __restrict__ v, const float* __restrict__ Wq,
    const float* __restrict__ Wk, const float* __restrict__ Wv,
    const float* __restrict__ v_param, float4* __restrict__ ab4,
    float2* __restrict__ ekT2, float* __restrict__ vp) {
  __shared__ float rows[PR_ROWS][D_MODEL];  // 32 KB
  const int tid = threadIdx.x;
  const int type = blockIdx.x >> 7;  // 128 row-groups per type
  const int r0 = (blockIdx.x & 127) * PR_ROWS;
  const float* __restrict__ in = (type == 0) ? q : (type == 1) ? k : v;
  const float* __restrict__ W = (type == 0) ? Wq : (type == 1) ? Wk : Wv;
  {
    const float4* __restrict__ in4 = (const float4*)(in + (size_t)r0 * D_MODEL);
    float4* r4 = (float4*)&rows[0][0];
#pragma unroll
    for (int t = 0; t < 8; ++t) r4[tid + 256 * t] = in4[tid + 256 * t];
  }
  __syncthreads();
  const int lane = tid & 63;
  const int wv = tid >> 6;        // 0..3
  const int rglob = r0 + wv * 4;  // wave's first global row (mult of 4)
  const float* __restrict__ Wl = W + lane;
  float c0[4] = {0.f, 0.f, 0.f, 0.f}, c1[4] = {0.f, 0.f, 0.f, 0.f};
#pragma unroll 4
  for (int e = 0; e < D_MODEL; e += 4) {
    float w0 = Wl[(size_t)(e + 0) * DK];
    float w1 = Wl[(size_t)(e + 1) * DK];
    float w2 = Wl[(size_t)(e + 2) * DK];
    float w3 = Wl[(size_t)(e + 3) * DK];
#pragma unroll
    for (int r = 0; r < 4; ++r) {
      float4 x = *(const float4*)&rows[wv * 4 + r][e];
      c0[r] = fmaf(x.x, w0, c0[r]);
      c1[r] = fmaf(x.y, w1, c1[r]);
      c0[r] = fmaf(x.z, w2, c0[r]);
      c1[r] = fmaf(x.w, w3, c1[r]);
    }
  }
  float acc[4];
#pragma unroll
  for (int r = 0; r < 4; ++r) acc[r] = c0[r] + c1[r];
  if (type == 0) {
    float vpar = v_param[lane];
#pragma unroll
    for (int r = 0; r < 4; ++r) {
      float iv = __builtin_amdgcn_exp2f(-L2E2 * acc[r]);
      float A = vpar * iv, B = iv;
      float Ah = __shfl_down(A, 32);  // lane d gets A_{d+32}
      float Bh = __shfl_down(B, 32);
      if (lane < 32)
        ab4[(size_t)(rglob + r) * 32 + lane] = make_float4(A, B, Ah, Bh);
    }
  } else if (type == 1) {
    float e4[4], h4[4];
#pragma unroll
    for (int r = 0; r < 4; ++r) {
      e4[r] = __builtin_amdgcn_exp2f(L2E2 * acc[r]);
      h4[r] = __shfl_down(e4[r], 32);  // lane d gets Ek[d+32]
    }
    if (lane < 32) {
      int b = rglob >> 10, j0 = rglob & 1023;  // rglob%4==0 -> 16B aligned
      float2* bp = ekT2 + (size_t)b * 32 * LK + (size_t)lane * LK + j0;
      *(float4*)bp = make_float4(e4[0], h4[0], e4[1], h4[1]);
      *(float4*)(bp + 2) = make_float4(e4[2], h4[2], e4[3], h4[3]);
    }
  } else {
#pragma unroll
    for (int r = 0; r < 4; ++r) vp[(size_t)(rglob + r) * DK + lane] = acc[r];
  }
}

// ---------------- fused scores + softmax + PV + FC + LN ----------------
// 256 thr (4 waves), RB=4 rows/block, grid 512 (r13-proven). Score: zero
// LDS, wave-uniform A/B s_loads, quad-rcp, f32 K. NEW vs r13: thread owns
// FOUR CONSECUTIVE j (4*tid..4*tid+3) -> per quad the 8 strided 8B loads
// become 4 contiguous 16B loads, and the 16 scalar stores become 4 float4
// stores (half the VMEM instrs, same bytes, still coalesced).
#define RB 4
__global__ __launch_bounds__(256, 4) void attn_kernel(
    const float4* __restrict__ ab4, const float2* __restrict__ ekT2,
    const float* __restrict__ vp, const float* __restrict__ resid,
    const float* __restrict__ Wfc, const float* __restrict__ gamma,
    const float* __restrict__ beta, float* __restrict__ out,
    float* __restrict__ attn_out) {
  __shared__ float sc[RB][LK];                  // 16 KB P rows
  __shared__ float4 pvred[4][RB][16];           // 4 KB PV partials
  __shared__ __align__(16) float ovlT[DK][RB];  // 1 KB, e-major
  __shared__ float red[2][RB][4];               // LN reductions
  __shared__ float mred[RB][4], sred[RB][4];
  const int tid = threadIdx.x;
  const int row0 = blockIdx.x * RB;  // RB | LQ -> single batch per block
  const int batch = row0 >> 10;
  const float2* __restrict__ ekT_b = ekT2 + (size_t)batch * 32 * LK;
  const float* __restrict__ vp_b = vp + (size_t)batch * LK * DK;
  const float4* __restrict__ abr0 = ab4 + (size_t)(row0 + 0) * 32;
  const float4* __restrict__ abr1 = ab4 + (size_t)(row0 + 1) * 32;
  const float4* __restrict__ abr2 = ab4 + (size_t)(row0 + 2) * 32;
  const float4* __restrict__ abr3 = ab4 + (size_t)(row0 + 3) * 32;

  float a0[4] = {0.f, 0.f, 0.f, 0.f};  // [jj] row 0, static-indexed
  float a1[4] = {0.f, 0.f, 0.f, 0.f};
  float a2[4] = {0.f, 0.f, 0.f, 0.f};
  float a3[4] = {0.f, 0.f, 0.f, 0.f};

#pragma unroll
  for (int qd = 0; qd < 16; ++qd) {  // quad covers dp = 2qd, 2qd+1
    // 4 consecutive j columns: {Ek[dp][j],Ek[dp+32][j]} pairs, 16B loads
    const float4* e0 =
        (const float4*)(ekT_b + (size_t)(2 * qd + 0) * LK + 4 * tid);
    const float4* e1 =
        (const float4*)(ekT_b + (size_t)(2 * qd + 1) * LK + 4 * tid);
    float4 ka = e0[0], kb = e0[1];  // (j0,j1) , (j2,j3) for row dp
    float4 kc = e1[0], kd = e1[1];  // same for row dp+1
    float2 k0[4], k1[4];
    k0[0] = make_float2(ka.x, ka.y); k0[1] = make_float2(ka.z, ka.w);
    k0[2] = make_float2(kb.x, kb.y); k0[3] = make_float2(kb.z, kb.w);
    k1[0] = make_float2(kc.x, kc.y); k1[1] = make_float2(kc.z, kc.w);
    k1[2] = make_float2(kd.x, kd.y); k1[3] = make_float2(kd.z, kd.w);
    // wave-uniform A/B loads (no tid in address -> scalarized)
    float4 P0 = abr0[2 * qd], Q0 = abr0[2 * qd + 1];
    float4 P1 = abr1[2 * qd], Q1 = abr1[2 * qd + 1];
    float4 P2 = abr2[2 * qd], Q2 = abr2[2 * qd + 1];
    float4 P3 = abr3[2 * qd], Q3 = abr3[2 * qd + 1];
#pragma unroll
    for (int jj = 0; jj < 4; ++jj) {
#define QUAD(PP, QQ, ACC)                                                  \
  {                                                                        \
    float x1 = k0[jj].x + PP.y, x2 = k0[jj].y + PP.w;                      \
    float x3 = k1[jj].x + QQ.y, x4 = k1[jj].y + QQ.w;                      \
    float p12 = x1 * x2, p34 = x3 * x4;                                    \
    float n12 = fmaf(PP.z, x1, PP.x * x2);                                 \
    float n34 = fmaf(QQ.z, x3, QQ.x * x4);                                 \
    float num = fmaf(n34, p12, n12 * p34);                                 \
    ACC[jj] = fmaf(num, __builtin_amdgcn_rcpf(p12 * p34), ACC[jj]);        \
  }
      QUAD(P0, Q0, a0)
      QUAD(P1, Q1, a1)
      QUAD(P2, Q2, a2)
      QUAD(P3, Q3, a3)
#undef QUAD
    }
  }

  const int wave = __builtin_amdgcn_readfirstlane(tid >> 6);
  const int lane = tid & 63;

  // softmax over score = C - 2*acc -> shift by min(acc); all waves, 4 rows
  {
    float pm0 = fminf(fminf(a0[0], a0[1]), fminf(a0[2], a0[3]));
    float pm1 = fminf(fminf(a1[0], a1[1]), fminf(a1[2], a1[3]));
    float pm2 = fminf(fminf(a2[0], a2[1]), fminf(a2[2], a2[3]));
    float pm3 = fminf(fminf(a3[0], a3[1]), fminf(a3[2], a3[3]));
#pragma unroll
    for (int off = 32; off > 0; off >>= 1) {
      pm0 = fminf(pm0, __shfl_xor(pm0, off));
      pm1 = fminf(pm1, __shfl_xor(pm1, off));
      pm2 = fminf(pm2, __shfl_xor(pm2, off));
      pm3 = fminf(pm3, __shfl_xor(pm3, off));
    }
    if (lane == 0) {
      mred[0][wave] = pm0; mred[1][wave] = pm1;
      mred[2][wave] = pm2; mred[3][wave] = pm3;
    }
    __syncthreads();
    float m0 = fminf(fminf(mred[0][0], mred[0][1]), fminf(mred[0][2], mred[0][3]));
    float m1 = fminf(fminf(mred[1][0], mred[1][1]), fminf(mred[1][2], mred[1][3]));
    float m2 = fminf(fminf(mred[2][0], mred[2][1]), fminf(mred[2][2], mred[2][3]));
    float m3 = fminf(fminf(mred[3][0], mred[3][1]), fminf(mred[3][2], mred[3][3]));
    float s0 = 0.f, s1 = 0.f, s2 = 0.f, s3 = 0.f;
#pragma unroll
    for (int jj = 0; jj < 4; ++jj) {
      a0[jj] = __builtin_amdgcn_exp2f((m0 - a0[jj]) * L2E2); s0 += a0[jj];
      a1[jj] = __builtin_amdgcn_exp2f((m1 - a1[jj]) * L2E2); s1 += a1[jj];
      a2[jj] = __builtin_amdgcn_exp2f((m2 - a2[jj]) * L2E2); s2 += a2[jj];
      a3[jj] = __builtin_amdgcn_exp2f((m3 - a3[jj]) * L2E2); s3 += a3[jj];
    }
#pragma unroll
    for (int off = 32; off > 0; off >>= 1) {
      s0 += __shfl_xor(s0, off); s1 += __shfl_xor(s1, off);
      s2 += __shfl_xor(s2, off); s3 += __shfl_xor(s3, off);
    }
    if (lane == 0) {
      sred[0][wave] = s0; sred[1][wave] = s1;
      sred[2][wave] = s2; sred[3][wave] = s3;
    }
    __syncthreads();
    float i0 = __builtin_amdgcn_rcpf(sred[0][0] + sred[0][1] + sred[0][2] + sred[0][3]);
    float i1 = __builtin_amdgcn_rcpf(sred[1][0] + sred[1][1] + sred[1][2] + sred[1][3]);
    float i2 = __builtin_amdgcn_rcpf(sred[2][0] + sred[2][1] + sred[2][2] + sred[2][3]);
    float i3 = __builtin_amdgcn_rcpf(sred[3][0] + sred[3][1] + sred[3][2] + sred[3][3]);
    // consecutive-j: one float4 store per row into sc and attn_out
    float4 p0 = make_float4(a0[0] * i0, a0[1] * i0, a0[2] * i0, a0[3] * i0);
    float4 p1 = make_float4(a1[0] * i1, a1[1] * i1, a1[2] * i1, a1[3] * i1);
    float4 p2 = make_float4(a2[0] * i2, a2[1] * i2, a2[2] * i2, a2[3] * i2);
    float4 p3 = make_float4(a3[0] * i3, a3[1] * i3, a3[2] * i3, a3[3] * i3);
    *(float4*)&sc[0][4 * tid] = p0;
    *(float4*)&sc[1][4 * tid] = p1;
    *(float4*)&sc[2][4 * tid] = p2;
    *(float4*)&sc[3][4 * tid] = p3;
    *(float4*)(attn_out + (size_t)(row0 + 0) * LK + 4 * tid) = p0;
    *(float4*)(attn_out + (size_t)(row0 + 1) * LK + 4 * tid) = p1;
    *(float4*)(attn_out + (size_t)(row0 + 2) * LK + 4 * tid) = p2;
    *(float4*)(attn_out + (size_t)(row0 + 3) * LK + 4 * tid) = p3;
  }
  __syncthreads();

  // PV: wave owns 256-j slice; vp read once per block per j (serves 4 rows)
  {
    const int jj = lane >> 4, l16 = lane & 15;
    const float4* __restrict__ vp4 = (const float4*)vp_b;
    float4 a[RB];
#pragma unroll
    for (int r = 0; r < RB; ++r) a[r] = make_float4(0.f, 0.f, 0.f, 0.f);
#pragma unroll 4
    for (int it = 0; it < 64; ++it) {
      int j = (wave << 8) + (it << 2) + jj;
      float4 vv = vp4[(size_t)j * (DK / 4) + l16];
#pragma unroll
      for (int r = 0; r < RB; ++r) {
        float pw = sc[r][j];
        a[r].x = fmaf(pw, vv.x, a[r].x);
        a[r].y = fmaf(pw, vv.y, a[r].y);
        a[r].z = fmaf(pw, vv.z, a[r].z);
        a[r].w = fmaf(pw, vv.w, a[r].w);
      }
    }
#pragma unroll
    for (int r = 0; r < RB; ++r) {
      a[r].x += __shfl_xor(a[r].x, 16); a[r].y += __shfl_xor(a[r].y, 16);
      a[r].z += __shfl_xor(a[r].z, 16); a[r].w += __shfl_xor(a[r].w, 16);
      a[r].x += __shfl_xor(a[r].x, 32); a[r].y += __shfl_xor(a[r].y, 32);
      a[r].z += __shfl_xor(a[r].z, 32); a[r].w += __shfl_xor(a[r].w, 32);
    }
    if (jj == 0) {
#pragma unroll
      for (int r = 0; r < RB; ++r) pvred[wave][r][l16] = a[r];
    }
  }
  __syncthreads();
  if (tid < 64) {  // final PV reduce -> transposed ovlT[e][r]
    int r = tid >> 4, l16 = tid & 15;
    float4 s = make_float4(0.f, 0.f, 0.f, 0.f);
#pragma unroll
    for (int w = 0; w < 4; ++w) {
      float4 t = pvred[w][r][l16];
      s.x += t.x; s.y += t.y; s.z += t.z; s.w += t.w;
    }
    ovlT[l16 * 4 + 0][r] = s.x;
    ovlT[l16 * 4 + 1][r] = s.y;
    ovlT[l16 * 4 + 2][r] = s.z;
    ovlT[l16 * 4 + 3][r] = s.w;
  }
  __syncthreads();

  // FC + residual + LN: thread owns columns c, c+256 of 4 rows
  {
    const int c0 = tid, c1 = tid + 256;
    float y[RB][2];
#pragma unroll
    for (int r = 0; r < RB; ++r) {
      y[r][0] = resid[(size_t)(row0 + r) * D_MODEL + c0];
      y[r][1] = resid[(size_t)(row0 + r) * D_MODEL + c1];
    }
#pragma unroll 4
    for (int e = 0; e < DK; ++e) {
      float w0 = Wfc[(size_t)e * D_MODEL + c0];
      float w1 = Wfc[(size_t)e * D_MODEL + c1];
      float4 ov = *(const float4*)&ovlT[e][0];
      y[0][0] = fmaf(ov.x, w0, y[0][0]); y[0][1] = fmaf(ov.x, w1, y[0][1]);
      y[1][0] = fmaf(ov.y, w0, y[1][0]); y[1][1] = fmaf(ov.y, w1, y[1][1]);
      y[2][0] = fmaf(ov.z, w0, y[2][0]); y[2][1] = fmaf(ov.z, w1, y[2][1]);
      y[3][0] = fmaf(ov.w, w0, y[3][0]); y[3][1] = fmaf(ov.w, w1, y[3][1]);
    }
#pragma unroll
    for (int r = 0; r < RB; ++r) {
      float s = y[r][0] + y[r][1];
#pragma unroll
      for (int off = 32; off > 0; off >>= 1) s += __shfl_xor(s, off);
      if (lane == 0) red[0][r][wave] = s;
    }
    __syncthreads();
    float mu[RB];
#pragma unroll
    for (int r = 0; r < RB; ++r)
      mu[r] = (red[0][r][0] + red[0][r][1] + red[0][r][2] + red[0][r][3]) *
              (1.0f / D_MODEL);
#pragma unroll
    for (int r = 0; r < RB; ++r) {
      float d0 = y[r][0] - mu[r], d1 = y[r][1] - mu[r];
      float s = d0 * d0 + d1 * d1;
#pragma unroll
      for (int off = 32; off > 0; off >>= 1) s += __shfl_xor(s, off);
      if (lane == 0) red[1][r][wave] = s;
    }
    __syncthreads();
    float g0 = gamma[c0], g1 = gamma[c1], b0 = beta[c0], b1 = beta[c1];
#pragma unroll
    for (int r = 0; r < RB; ++r) {
      float var = (red[1][r][0] + red[1][r][1] + red[1][r][2] + red[1][r][3]) *
                  (1.0f / D_MODEL);
      float rstd = rsqrtf(var + LN_EPS);
      out[(size_t)(row0 + r) * D_MODEL + c0] = (y[r][0] - mu[r]) * rstd * g0 + b0;
      out[(size_t)(row0 + r) * D_MODEL + c1] = (y[r][1] - mu[r]) * rstd * g1 + b1;
    }
  }
}

extern "C" void kernel_launch(void* const* d_in, const int* in_sizes, int n_in,
                              void* d_out, int out_size, void* d_ws,
                              size_t ws_size, hipStream_t stream) {
  const float* q = (const float*)d_in[0];
  const float* k = (const float*)d_in[1];
  const float* v = (const float*)d_in[2];
  const float* Wq = (const float*)d_in[3];
  const float* Wk = (const float*)d_in[4];
  const float* Wv = (const float*)d_in[5];
  const float* v_param = (const float*)d_in[6];
  const float* Wfc = (const float*)d_in[7];
  const float* gamma = (const float*)d_in[8];
  const float* beta = (const float*)d_in[9];

  float* out = (float*)d_out;                     // [B*LQ*D_MODEL]
  float* attn = out + (size_t)NB * LQ * D_MODEL;  // [B*LQ*LK]

  float* base = (float*)d_ws;
  float4* ab4 = (float4*)base;                    // 2048*32 float4 (1 MB)
  float* p1 = base + (size_t)NB * LQ * 32 * 4;    // floats consumed by ab4
  float2* ekT2 = (float2*)p1;                     // 2*32*1024 float2 (512 KB)
  float* vp = p1 + (size_t)NB * 32 * LK * 2;      // [2048*64]

  hipLaunchKernelGGL(proj_kernel, dim3(3 * 128), dim3(256), 0, stream, q, k, v,
                     Wq, Wk, Wv, v_param, ab4, ekT2, vp);
  hipLaunchKernelGGL(attn_kernel, dim3(NB * LQ / RB), dim3(256), 0, stream,
                     ab4, ekT2, vp, q, Wfc, gamma, beta, out, attn);
}

// Round 16
// 55.209 us; speedup vs baseline: 1.1071x; 1.0091x over previous
//
#include <hip/hip_runtime.h>
#include <cstddef>
#include <cstdint>

#define D_MODEL 512
#define DK 64
#define LQ 1024
#define LK 1024
#define NB 2
#define LN_EPS 1e-6f
#define L2E2 2.8853900817779268f  // 2*log2(e)

// ---------------- projections ----------------
// type 0: qp=q@Wq -> ab4[row][dp] = float4{A_dp, B_dp, A_dp+32, B_dp+32}
//         with A = v_d*e^{-2qp}, B = e^{-2qp}
// type 1: ek=e^{2*(k@Wk)} -> ekT2[batch][dp][j] = float2{ek[dp], ek[dp+32]}
// type 2: vp = v@Wv (f32 row-major)
// r13-proven shape: 256 thr (4 waves), 16 rows/block (4/wave), grid 384,
// rows staged in LDS (b128 broadcasts), W per-lane coalesced.
#define PR_ROWS 16
__global__ __launch_bounds__(256, 4) void proj_kernel(
    const float* __restrict__ q, const float* __restrict__ k,
    const float* __restrict__ v, const float* __restrict__ Wq,
    const float* __restrict__ Wk, const float* __restrict__ Wv,
    const float* __restrict__ v_param, float4* __restrict__ ab4,
    float2* __restrict__ ekT2, float* __restrict__ vp) {
  __shared__ float rows[PR_ROWS][D_MODEL];  // 32 KB
  const int tid = threadIdx.x;
  const int type = blockIdx.x >> 7;  // 128 row-groups per type
  const int r0 = (blockIdx.x & 127) * PR_ROWS;
  const float* __restrict__ in = (type == 0) ? q : (type == 1) ? k : v;
  const float* __restrict__ W = (type == 0) ? Wq : (type == 1) ? Wk : Wv;
  {
    const float4* __restrict__ in4 = (const float4*)(in + (size_t)r0 * D_MODEL);
    float4* r4 = (float4*)&rows[0][0];
#pragma unroll
    for (int t = 0; t < 8; ++t) r4[tid + 256 * t] = in4[tid + 256 * t];
  }
  __syncthreads();
  const int lane = tid & 63;
  const int wv = tid >> 6;        // 0..3
  const int rglob = r0 + wv * 4;  // wave's first global row (mult of 4)
  const float* __restrict__ Wl = W + lane;
  float c0[4] = {0.f, 0.f, 0.f, 0.f}, c1[4] = {0.f, 0.f, 0.f, 0.f};
#pragma unroll 4
  for (int e = 0; e < D_MODEL; e += 4) {
    float w0 = Wl[(size_t)(e + 0) * DK];
    float w1 = Wl[(size_t)(e + 1) * DK];
    float w2 = Wl[(size_t)(e + 2) * DK];
    float w3 = Wl[(size_t)(e + 3) * DK];
#pragma unroll
    for (int r = 0; r < 4; ++r) {
      float4 x = *(const float4*)&rows[wv * 4 + r][e];
      c0[r] = fmaf(x.x, w0, c0[r]);
      c1[r] = fmaf(x.y, w1, c1[r]);
      c0[r] = fmaf(x.z, w2, c0[r]);
      c1[r] = fmaf(x.w, w3, c1[r]);
    }
  }
  float acc[4];
#pragma unroll
  for (int r = 0; r < 4; ++r) acc[r] = c0[r] + c1[r];
  if (type == 0) {
    float vpar = v_param[lane];
#pragma unroll
    for (int r = 0; r < 4; ++r) {
      float iv = __builtin_amdgcn_exp2f(-L2E2 * acc[r]);
      float A = vpar * iv, B = iv;
      float Ah = __shfl_down(A, 32);  // lane d gets A_{d+32}
      float Bh = __shfl_down(B, 32);
      if (lane < 32)
        ab4[(size_t)(rglob + r) * 32 + lane] = make_float4(A, B, Ah, Bh);
    }
  } else if (type == 1) {
    float e4[4], h4[4];
#pragma unroll
    for (int r = 0; r < 4; ++r) {
      e4[r] = __builtin_amdgcn_exp2f(L2E2 * acc[r]);
      h4[r] = __shfl_down(e4[r], 32);  // lane d gets Ek[d+32]
    }
    if (lane < 32) {
      int b = rglob >> 10, j0 = rglob & 1023;  // rglob%4==0 -> 16B aligned
      float2* bp = ekT2 + (size_t)b * 32 * LK + (size_t)lane * LK + j0;
      *(float4*)bp = make_float4(e4[0], h4[0], e4[1], h4[1]);
      *(float4*)(bp + 2) = make_float4(e4[2], h4[2], e4[3], h4[3]);
    }
  } else {
#pragma unroll
    for (int r = 0; r < 4; ++r) vp[(size_t)(rglob + r) * DK + lane] = acc[r];
  }
}

// ---------------- fused scores + softmax + PV + FC + LN ----------------
// 256 thr (4 waves), RB=2 rows/block, grid 1024 -> 4 blocks/CU = 16
// waves/CU (r15 lesson: occupancy was GRID-capped at 2 blocks/CU; this is
// the clean 2x-TLP experiment with per-thread ILP preserved at 4 j).
// Score: zero LDS, wave-uniform A/B s_loads, quad-rcp, f32 K, 4
// consecutive j per thread (16B loads/stores).
#define RB 2
__global__ __launch_bounds__(256, 6) void attn_kernel(
    const float4* __restrict__ ab4, const float2* __restrict__ ekT2,
    const float* __restrict__ vp, const float* __restrict__ resid,
    const float* __restrict__ Wfc, const float* __restrict__ gamma,
    const float* __restrict__ beta, float* __restrict__ out,
    float* __restrict__ attn_out) {
  __shared__ float sc[RB][LK];                  // 8 KB P rows
  __shared__ float4 pvred[4][RB][16];           // 2 KB PV partials
  __shared__ __align__(16) float ovlT[DK][RB];  // 0.5 KB, e-major
  __shared__ float red[2][RB][4];               // LN reductions
  __shared__ float mred[RB][4], sred[RB][4];
  const int tid = threadIdx.x;
  const int row0 = blockIdx.x * RB;  // RB | LQ -> single batch per block
  const int batch = row0 >> 10;
  const float2* __restrict__ ekT_b = ekT2 + (size_t)batch * 32 * LK;
  const float* __restrict__ vp_b = vp + (size_t)batch * LK * DK;
  const float4* __restrict__ abr0 = ab4 + (size_t)(row0 + 0) * 32;
  const float4* __restrict__ abr1 = ab4 + (size_t)(row0 + 1) * 32;

  float a0[4] = {0.f, 0.f, 0.f, 0.f};  // [jj] row 0, static-indexed
  float a1[4] = {0.f, 0.f, 0.f, 0.f};

#pragma unroll
  for (int qd = 0; qd < 16; ++qd) {  // quad covers dp = 2qd, 2qd+1
    // 4 consecutive j columns: {Ek[dp][j],Ek[dp+32][j]} pairs, 16B loads
    const float4* e0 =
        (const float4*)(ekT_b + (size_t)(2 * qd + 0) * LK + 4 * tid);
    const float4* e1 =
        (const float4*)(ekT_b + (size_t)(2 * qd + 1) * LK + 4 * tid);
    float4 ka = e0[0], kb = e0[1];  // (j0,j1) , (j2,j3) for row dp
    float4 kc = e1[0], kd = e1[1];  // same for row dp+1
    float2 k0[4], k1[4];
    k0[0] = make_float2(ka.x, ka.y); k0[1] = make_float2(ka.z, ka.w);
    k0[2] = make_float2(kb.x, kb.y); k0[3] = make_float2(kb.z, kb.w);
    k1[0] = make_float2(kc.x, kc.y); k1[1] = make_float2(kc.z, kc.w);
    k1[2] = make_float2(kd.x, kd.y); k1[3] = make_float2(kd.z, kd.w);
    // wave-uniform A/B loads (no tid in address -> scalarized)
    float4 P0 = abr0[2 * qd], Q0 = abr0[2 * qd + 1];
    float4 P1 = abr1[2 * qd], Q1 = abr1[2 * qd + 1];
#pragma unroll
    for (int jj = 0; jj < 4; ++jj) {
#define QUAD(PP, QQ, ACC)                                                  \
  {                                                                        \
    float x1 = k0[jj].x + PP.y, x2 = k0[jj].y + PP.w;                      \
    float x3 = k1[jj].x + QQ.y, x4 = k1[jj].y + QQ.w;                      \
    float p12 = x1 * x2, p34 = x3 * x4;                                    \
    float n12 = fmaf(PP.z, x1, PP.x * x2);                                 \
    float n34 = fmaf(QQ.z, x3, QQ.x * x4);                                 \
    float num = fmaf(n34, p12, n12 * p34);                                 \
    ACC[jj] = fmaf(num, __builtin_amdgcn_rcpf(p12 * p34), ACC[jj]);        \
  }
      QUAD(P0, Q0, a0)
      QUAD(P1, Q1, a1)
#undef QUAD
    }
  }

  const int wave = __builtin_amdgcn_readfirstlane(tid >> 6);
  const int lane = tid & 63;

  // softmax over score = C - 2*acc -> shift by min(acc)
  {
    float pm0 = fminf(fminf(a0[0], a0[1]), fminf(a0[2], a0[3]));
    float pm1 = fminf(fminf(a1[0], a1[1]), fminf(a1[2], a1[3]));
#pragma unroll
    for (int off = 32; off > 0; off >>= 1) {
      pm0 = fminf(pm0, __shfl_xor(pm0, off));
      pm1 = fminf(pm1, __shfl_xor(pm1, off));
    }
    if (lane == 0) {
      mred[0][wave] = pm0;
      mred[1][wave] = pm1;
    }
    __syncthreads();
    float m0 = fminf(fminf(mred[0][0], mred[0][1]), fminf(mred[0][2], mred[0][3]));
    float m1 = fminf(fminf(mred[1][0], mred[1][1]), fminf(mred[1][2], mred[1][3]));
    float s0 = 0.f, s1 = 0.f;
#pragma unroll
    for (int jj = 0; jj < 4; ++jj) {
      a0[jj] = __builtin_amdgcn_exp2f((m0 - a0[jj]) * L2E2); s0 += a0[jj];
      a1[jj] = __builtin_amdgcn_exp2f((m1 - a1[jj]) * L2E2); s1 += a1[jj];
    }
#pragma unroll
    for (int off = 32; off > 0; off >>= 1) {
      s0 += __shfl_xor(s0, off);
      s1 += __shfl_xor(s1, off);
    }
    if (lane == 0) {
      sred[0][wave] = s0;
      sred[1][wave] = s1;
    }
    __syncthreads();
    float i0 = __builtin_amdgcn_rcpf(sred[0][0] + sred[0][1] + sred[0][2] + sred[0][3]);
    float i1 = __builtin_amdgcn_rcpf(sred[1][0] + sred[1][1] + sred[1][2] + sred[1][3]);
    // consecutive-j: one float4 store per row into sc and attn_out
    float4 p0 = make_float4(a0[0] * i0, a0[1] * i0, a0[2] * i0, a0[3] * i0);
    float4 p1 = make_float4(a1[0] * i1, a1[1] * i1, a1[2] * i1, a1[3] * i1);
    *(float4*)&sc[0][4 * tid] = p0;
    *(float4*)&sc[1][4 * tid] = p1;
    *(float4*)(attn_out + (size_t)(row0 + 0) * LK + 4 * tid) = p0;
    *(float4*)(attn_out + (size_t)(row0 + 1) * LK + 4 * tid) = p1;
  }
  __syncthreads();

  // PV: wave owns 256-j slice; vp read once per block per j (serves 2 rows)
  {
    const int jj = lane >> 4, l16 = lane & 15;
    const float4* __restrict__ vp4 = (const float4*)vp_b;
    float4 a[RB];
#pragma unroll
    for (int r = 0; r < RB; ++r) a[r] = make_float4(0.f, 0.f, 0.f, 0.f);
#pragma unroll 4
    for (int it = 0; it < 64; ++it) {
      int j = (wave << 8) + (it << 2) + jj;
      float4 vv = vp4[(size_t)j * (DK / 4) + l16];
#pragma unroll
      for (int r = 0; r < RB; ++r) {
        float pw = sc[r][j];
        a[r].x = fmaf(pw, vv.x, a[r].x);
        a[r].y = fmaf(pw, vv.y, a[r].y);
        a[r].z = fmaf(pw, vv.z, a[r].z);
        a[r].w = fmaf(pw, vv.w, a[r].w);
      }
    }
#pragma unroll
    for (int r = 0; r < RB; ++r) {
      a[r].x += __shfl_xor(a[r].x, 16); a[r].y += __shfl_xor(a[r].y, 16);
      a[r].z += __shfl_xor(a[r].z, 16); a[r].w += __shfl_xor(a[r].w, 16);
      a[r].x += __shfl_xor(a[r].x, 32); a[r].y += __shfl_xor(a[r].y, 32);
      a[r].z += __shfl_xor(a[r].z, 32); a[r].w += __shfl_xor(a[r].w, 32);
    }
    if (jj == 0) {
#pragma unroll
      for (int r = 0; r < RB; ++r) pvred[wave][r][l16] = a[r];
    }
  }
  __syncthreads();
  if (tid < 32) {  // final PV reduce -> transposed ovlT[e][r]
    int r = tid >> 4, l16 = tid & 15;
    float4 s = make_float4(0.f, 0.f, 0.f, 0.f);
#pragma unroll
    for (int w = 0; w < 4; ++w) {
      float4 t = pvred[w][r][l16];
      s.x += t.x; s.y += t.y; s.z += t.z; s.w += t.w;
    }
    ovlT[l16 * 4 + 0][r] = s.x;
    ovlT[l16 * 4 + 1][r] = s.y;
    ovlT[l16 * 4 + 2][r] = s.z;
    ovlT[l16 * 4 + 3][r] = s.w;
  }
  __syncthreads();

  // FC + residual + LN: thread owns columns c, c+256 of 2 rows
  {
    const int c0 = tid, c1 = tid + 256;
    float y[RB][2];
#pragma unroll
    for (int r = 0; r < RB; ++r) {
      y[r][0] = resid[(size_t)(row0 + r) * D_MODEL + c0];
      y[r][1] = resid[(size_t)(row0 + r) * D_MODEL + c1];
    }
#pragma unroll 4
    for (int e = 0; e < DK; ++e) {
      float w0 = Wfc[(size_t)e * D_MODEL + c0];
      float w1 = Wfc[(size_t)e * D_MODEL + c1];
      float2 ov = *(const float2*)&ovlT[e][0];
      y[0][0] = fmaf(ov.x, w0, y[0][0]); y[0][1] = fmaf(ov.x, w1, y[0][1]);
      y[1][0] = fmaf(ov.y, w0, y[1][0]); y[1][1] = fmaf(ov.y, w1, y[1][1]);
    }
#pragma unroll
    for (int r = 0; r < RB; ++r) {
      float s = y[r][0] + y[r][1];
#pragma unroll
      for (int off = 32; off > 0; off >>= 1) s += __shfl_xor(s, off);
      if (lane == 0) red[0][r][wave] = s;
    }
    __syncthreads();
    float mu[RB];
#pragma unroll
    for (int r = 0; r < RB; ++r)
      mu[r] = (red[0][r][0] + red[0][r][1] + red[0][r][2] + red[0][r][3]) *
              (1.0f / D_MODEL);
#pragma unroll
    for (int r = 0; r < RB; ++r) {
      float d0 = y[r][0] - mu[r], d1 = y[r][1] - mu[r];
      float s = d0 * d0 + d1 * d1;
#pragma unroll
      for (int off = 32; off > 0; off >>= 1) s += __shfl_xor(s, off);
      if (lane == 0) red[1][r][wave] = s;
    }
    __syncthreads();
    float g0 = gamma[c0], g1 = gamma[c1], b0 = beta[c0], b1 = beta[c1];
#pragma unroll
    for (int r = 0; r < RB; ++r) {
      float var = (red[1][r][0] + red[1][r][1] + red[1][r][2] + red[1][r][3]) *
                  (1.0f / D_MODEL);
      float rstd = rsqrtf(var + LN_EPS);
      out[(size_t)(row0 + r) * D_MODEL + c0] = (y[r][0] - mu[r]) * rstd * g0 + b0;
      out[(size_t)(row0 + r) * D_MODEL + c1] = (y[r][1] - mu[r]) * rstd * g1 + b1;
    }
  }
}

extern "C" void kernel_launch(void* const* d_in, const int* in_sizes, int n_in,
                              void* d_out, int out_size, void* d_ws,
                              size_t ws_size, hipStream_t stream) {
  const float* q = (const float*)d_in[0];
  const float* k = (const float*)d_in[1];
  const float* v = (const float*)d_in[2];
  const float* Wq = (const float*)d_in[3];
  const float* Wk = (const float*)d_in[4];
  const float* Wv = (const float*)d_in[5];
  const float* v_param = (const float*)d_in[6];
  const float* Wfc = (const float*)d_in[7];
  const float* gamma = (const float*)d_in[8];
  const float* beta = (const float*)d_in[9];

  float* out = (float*)d_out;                     // [B*LQ*D_MODEL]
  float* attn = out + (size_t)NB * LQ * D_MODEL;  // [B*LQ*LK]

  float* base = (float*)d_ws;
  float4* ab4 = (float4*)base;                    // 2048*32 float4 (1 MB)
  float* p1 = base + (size_t)NB * LQ * 32 * 4;    // floats consumed by ab4
  float2* ekT2 = (float2*)p1;                     // 2*32*1024 float2 (512 KB)
  float* vp = p1 + (size_t)NB * 32 * LK * 2;      // [2048*64]

  hipLaunchKernelGGL(proj_kernel, dim3(3 * 128), dim3(256), 0, stream, q, k, v,
                     Wq, Wk, Wv, v_param, ab4, ekT2, vp);
  hipLaunchKernelGGL(attn_kernel, dim3(NB * LQ / RB), dim3(256), 0, stream,
                     ab4, ekT2, vp, q, Wfc, gamma, beta, out, attn);
}